// Round 1
// 548.729 us; speedup vs baseline: 1.0629x; 1.0629x over previous
//
#include <hip/hip_runtime.h>
#include <cstddef>

#define N_NODES  100000
#define N_EDGES  600000
#define N_GRAPHS 64

__device__ __forceinline__ void atomAddF(float* p, float v) {
    // gfx950 has HW global fp32 atomic add; unsafeAtomicAdd guarantees the HW path.
    unsafeAtomicAdd(p, v);
}

// ---------------------------------------------------------------------------
// deg[n] = in-degree (int)
__global__ __launch_bounds__(256) void deg_count(const int* __restrict__ dst,
                                                 int* __restrict__ deg) {
    int e = blockIdx.x * 256 + threadIdx.x;
    if (e < N_EDGES) atomicAdd(deg + dst[e], 1);
}

// ---------------------------------------------------------------------------
// off[n] = exclusive prefix sum of deg (CSR start offsets). Single block, 1024 thr.
__global__ __launch_bounds__(1024)
void scan_off(const int* __restrict__ deg, int* __restrict__ off) {
    __shared__ int s[1024];
    const int t  = threadIdx.x;
    const int CH = (N_NODES + 1023) / 1024;   // 98 nodes per thread
    int lo = t * CH, hi = min(lo + CH, N_NODES);
    int sum = 0;
    for (int n = lo; n < hi; ++n) sum += deg[n];
    s[t] = sum;
    __syncthreads();
    for (int d = 1; d < 1024; d <<= 1) {      // Hillis-Steele inclusive scan
        int v = (t >= d) ? s[t - d] : 0;
        __syncthreads();
        s[t] += v;
        __syncthreads();
    }
    int base = (t == 0) ? 0 : s[t - 1];
    for (int n = lo; n < hi; ++n) { off[n] = base; base += deg[n]; }
}

// ---------------------------------------------------------------------------
// CSR fill: csr_src[off[d]++] = src[e].  Afterwards off[n] = END offset of node n
// (start of node n is off[n-1], or 0 for n==0) -- no separate cursor array needed.
__global__ __launch_bounds__(256)
void csr_fill(const int* __restrict__ src, const int* __restrict__ dst,
              int* __restrict__ off, int* __restrict__ csr_src) {
    int e = blockIdx.x * 256 + threadIdx.x;
    if (e >= N_EDGES) return;
    int p = atomicAdd(off + dst[e], 1);
    csr_src[p] = src[e];
}

// ---------------------------------------------------------------------------
// GEMM1: C[100000 x 200] = feat[100000 x 128] @ [Wself1 | Wneigh1]
// cols 0..99 -> S1, 100..199 -> N1.  BM=64, BN=64, 256 thr (16x16), TM=TN=4.
__global__ __launch_bounds__(256)
void gemm1(const float* __restrict__ feat, const float* __restrict__ Wself,
           const float* __restrict__ Wneigh,
           float* __restrict__ S1, float* __restrict__ N1) {
    __shared__ float As[64][132];   // [m][k], pad 132: A-col reads 2-way (free), rows 16B aligned
    __shared__ float Bs[128][64];   // [k][n]
    const int tid = threadIdx.x;
    const int m0  = blockIdx.x * 64;
    const int n0  = blockIdx.y * 64;   // 0,64,128,192

    // A tile: 64 rows x 32 float4 (k), coalesced
#pragma unroll
    for (int i = 0; i < 8; ++i) {
        int idx = tid + 256 * i;
        int r = idx >> 5, k4 = idx & 31;
        int gr = m0 + r;
        float4 v = make_float4(0.f, 0.f, 0.f, 0.f);
        if (gr < N_NODES)
            v = reinterpret_cast<const float4*>(feat)[(size_t)gr * 32 + k4];
        *reinterpret_cast<float4*>(&As[r][k4 * 4]) = v;
    }
    // B tile: 128 k x 16 float4 (n); cols >=200 zero-padded
#pragma unroll
    for (int i = 0; i < 8; ++i) {
        int idx = tid + 256 * i;
        int k = idx >> 4, n4 = idx & 15;
        int n = n0 + n4 * 4;
        float4 v = make_float4(0.f, 0.f, 0.f, 0.f);
        if (n < 100)       v = *reinterpret_cast<const float4*>(Wself + k * 100 + n);
        else if (n < 200)  v = *reinterpret_cast<const float4*>(Wneigh + k * 100 + (n - 100));
        *reinterpret_cast<float4*>(&Bs[k][n4 * 4]) = v;
    }
    __syncthreads();

    const int tr = tid >> 4, tc = tid & 15;
    float acc[4][4] = {};
#pragma unroll 4
    for (int k = 0; k < 128; ++k) {
        float a0 = As[tr * 4 + 0][k];
        float a1 = As[tr * 4 + 1][k];
        float a2 = As[tr * 4 + 2][k];
        float a3 = As[tr * 4 + 3][k];
        float4 b = *reinterpret_cast<const float4*>(&Bs[k][tc * 4]);
        acc[0][0] += a0 * b.x; acc[0][1] += a0 * b.y; acc[0][2] += a0 * b.z; acc[0][3] += a0 * b.w;
        acc[1][0] += a1 * b.x; acc[1][1] += a1 * b.y; acc[1][2] += a1 * b.z; acc[1][3] += a1 * b.w;
        acc[2][0] += a2 * b.x; acc[2][1] += a2 * b.y; acc[2][2] += a2 * b.z; acc[2][3] += a2 * b.w;
        acc[3][0] += a3 * b.x; acc[3][1] += a3 * b.y; acc[3][2] += a3 * b.z; acc[3][3] += a3 * b.w;
    }

#pragma unroll
    for (int i = 0; i < 4; ++i) {
        int gr = m0 + tr * 4 + i;
        if (gr >= N_NODES) continue;
        int n = n0 + tc * 4;
        float4 v = make_float4(acc[i][0], acc[i][1], acc[i][2], acc[i][3]);
        if (n < 100)       *reinterpret_cast<float4*>(S1 + (size_t)gr * 100 + n) = v;
        else if (n < 200)  *reinterpret_cast<float4*>(N1 + (size_t)gr * 100 + (n - 100)) = v;
    }
}

// ---------------------------------------------------------------------------
// aggregate1: A1[n][c] = sum over in-edges of N1[src][c].  Gather via CSR,
// zero float atomics, writes every row (zero-degree rows -> 0, replaces memset).
// 128 threads per node (100 live cols), 2 nodes per 256-block.
__global__ __launch_bounds__(256)
void aggregate1(const float* __restrict__ N1, const int* __restrict__ csr_src,
                const int* __restrict__ off, float* __restrict__ A1) {
    int n = blockIdx.x * 2 + (threadIdx.x >> 7);
    int c = threadIdx.x & 127;
    if (n >= N_NODES || c >= 100) return;
    int beg = (n == 0) ? 0 : off[n - 1];
    int end = off[n];
    float acc = 0.f;
    int j = beg;
    for (; j + 1 < end; j += 2) {           // unroll x2 for load pipelining
        int s0 = csr_src[j], s1 = csr_src[j + 1];
        acc += N1[(size_t)s0 * 100 + c] + N1[(size_t)s1 * 100 + c];
    }
    if (j < end) acc += N1[(size_t)csr_src[j] * 100 + c];
    A1[(size_t)n * 100 + c] = acc;
}

// ---------------------------------------------------------------------------
// GEMM2: h1 = relu(S1 + A1*inv_deg + b1) fused into A-tile load;
// C[100000 x 40] = h1 @ [Wself2 | Wneigh2].  BM=64, BN=64(40 live), K=100.
__global__ __launch_bounds__(256)
void gemm2(const float* __restrict__ S1, const float* __restrict__ A1,
           const int* __restrict__ deg, const float* __restrict__ b1,
           const float* __restrict__ Ws2, const float* __restrict__ Wn2,
           float* __restrict__ S2, float* __restrict__ N2) {
    __shared__ float As[64][108];   // [m][k], K=100 padded to 108 (aligned, 2-way reads)
    __shared__ float Bs[100][64];
    const int tid = threadIdx.x;
    const int m0  = blockIdx.x * 64;

    for (int idx = tid; idx < 100 * 16; idx += 256) {   // B tile
        int k = idx >> 4, n4 = idx & 15;
        int n = n4 * 4;
        float4 v = make_float4(0.f, 0.f, 0.f, 0.f);
        if (n < 20)       v = *reinterpret_cast<const float4*>(Ws2 + k * 20 + n);
        else if (n < 40)  v = *reinterpret_cast<const float4*>(Wn2 + k * 20 + (n - 20));
        *reinterpret_cast<float4*>(&Bs[k][n]) = v;
    }
    for (int idx = tid; idx < 64 * 25; idx += 256) {    // A tile (fused h1)
        int r = idx / 25, k4 = idx % 25;
        int gr = m0 + r;
        float4 h = make_float4(0.f, 0.f, 0.f, 0.f);
        if (gr < N_NODES) {
            float4 s  = *reinterpret_cast<const float4*>(S1 + (size_t)gr * 100 + k4 * 4);
            float4 a  = *reinterpret_cast<const float4*>(A1 + (size_t)gr * 100 + k4 * 4);
            float4 bb = *reinterpret_cast<const float4*>(b1 + k4 * 4);
            float inv = 1.0f / (float)max(deg[gr], 1);
            h.x = fmaxf(fmaf(a.x, inv, s.x) + bb.x, 0.f);
            h.y = fmaxf(fmaf(a.y, inv, s.y) + bb.y, 0.f);
            h.z = fmaxf(fmaf(a.z, inv, s.z) + bb.z, 0.f);
            h.w = fmaxf(fmaf(a.w, inv, s.w) + bb.w, 0.f);
        }
        *reinterpret_cast<float4*>(&As[r][k4 * 4]) = h;
    }
    __syncthreads();

    const int tr = tid >> 4, tc = tid & 15;
    float acc[4][4] = {};
#pragma unroll 4
    for (int k = 0; k < 100; ++k) {
        float a0 = As[tr * 4 + 0][k];
        float a1 = As[tr * 4 + 1][k];
        float a2 = As[tr * 4 + 2][k];
        float a3 = As[tr * 4 + 3][k];
        float4 b = *reinterpret_cast<const float4*>(&Bs[k][tc * 4]);
        acc[0][0] += a0 * b.x; acc[0][1] += a0 * b.y; acc[0][2] += a0 * b.z; acc[0][3] += a0 * b.w;
        acc[1][0] += a1 * b.x; acc[1][1] += a1 * b.y; acc[1][2] += a1 * b.z; acc[1][3] += a1 * b.w;
        acc[2][0] += a2 * b.x; acc[2][1] += a2 * b.y; acc[2][2] += a2 * b.z; acc[2][3] += a2 * b.w;
        acc[3][0] += a3 * b.x; acc[3][1] += a3 * b.y; acc[3][2] += a3 * b.z; acc[3][3] += a3 * b.w;
    }

#pragma unroll
    for (int i = 0; i < 4; ++i) {
        int gr = m0 + tr * 4 + i;
        if (gr >= N_NODES) continue;
        int n = tc * 4;
        float4 v = make_float4(acc[i][0], acc[i][1], acc[i][2], acc[i][3]);
        if (n < 20)       *reinterpret_cast<float4*>(S2 + (size_t)gr * 20 + n) = v;
        else if (n < 40)  *reinterpret_cast<float4*>(N2 + (size_t)gr * 20 + (n - 20)) = v;
    }
}

// ---------------------------------------------------------------------------
// aggregate2: A2[n][c] = sum over in-edges of N2[src][c].  32 thr/node (20 live),
// 8 nodes per 256-block.  Zero atomics, replaces scatter2 + A2 memset.
__global__ __launch_bounds__(256)
void aggregate2(const float* __restrict__ N2, const int* __restrict__ csr_src,
                const int* __restrict__ off, float* __restrict__ A2) {
    int n = blockIdx.x * 8 + (threadIdx.x >> 5);
    int c = threadIdx.x & 31;
    if (n >= N_NODES || c >= 20) return;
    int beg = (n == 0) ? 0 : off[n - 1];
    int end = off[n];
    float acc = 0.f;
    int j = beg;
    for (; j + 1 < end; j += 2) {
        int s0 = csr_src[j], s1 = csr_src[j + 1];
        acc += N2[(size_t)s0 * 20 + c] + N2[(size_t)s1 * 20 + c];
    }
    if (j < end) acc += N2[(size_t)csr_src[j] * 20 + c];
    A2[(size_t)n * 20 + c] = acc;
}

// ---------------------------------------------------------------------------
// pool: h2 = relu(S2 + A2*inv + b2); per-graph sums + counts.
// graph_ids sorted -> most waves uniform -> wave shfl-reduce, 20 atomics/wave.
__global__ __launch_bounds__(256)
void pool_kernel(const float* __restrict__ S2, const float* __restrict__ A2,
                 const int* __restrict__ deg, const float* __restrict__ b2,
                 const int* __restrict__ gids,
                 float* __restrict__ pool, float* __restrict__ cnt) {
    int n = blockIdx.x * 256 + threadIdx.x;
    float h[20];
    int g = -1;
    if (n < N_NODES) {
        g = gids[n];
        float inv = 1.0f / (float)max(deg[n], 1);
#pragma unroll
        for (int q = 0; q < 5; ++q) {
            float4 s = *reinterpret_cast<const float4*>(S2 + (size_t)n * 20 + q * 4);
            float4 a = *reinterpret_cast<const float4*>(A2 + (size_t)n * 20 + q * 4);
            float4 bb = *reinterpret_cast<const float4*>(b2 + q * 4);
            h[q * 4 + 0] = fmaxf(fmaf(a.x, inv, s.x) + bb.x, 0.f);
            h[q * 4 + 1] = fmaxf(fmaf(a.y, inv, s.y) + bb.y, 0.f);
            h[q * 4 + 2] = fmaxf(fmaf(a.z, inv, s.z) + bb.z, 0.f);
            h[q * 4 + 3] = fmaxf(fmaf(a.w, inv, s.w) + bb.w, 0.f);
        }
    } else {
#pragma unroll
        for (int c = 0; c < 20; ++c) h[c] = 0.f;
    }
    unsigned long long act = __ballot(n < N_NODES);
    int gfirst = __shfl(g, 0);
    bool uniform = __all(g == gfirst);
    if (uniform) {
        if (gfirst >= 0) {
#pragma unroll
            for (int c = 0; c < 20; ++c)
                for (int off2 = 32; off2 > 0; off2 >>= 1)
                    h[c] += __shfl_down(h[c], off2);
            if ((threadIdx.x & 63) == 0) {
                for (int c = 0; c < 20; ++c) atomAddF(&pool[gfirst * 20 + c], h[c]);
                atomAddF(&cnt[gfirst], (float)__popcll(act));
            }
        }
    } else if (n < N_NODES) {
        for (int c = 0; c < 20; ++c) atomAddF(&pool[g * 20 + c], h[c]);
        atomAddF(&cnt[g], 1.0f);
    }
}

// ---------------------------------------------------------------------------
// head: hg = pool/cnt; out = relu(hg@fc1+b1)@fc2+b2.  One block, thread per graph.
__global__ __launch_bounds__(64)
void head(const float* __restrict__ pool, const float* __restrict__ cnt,
          const float* __restrict__ fc1w, const float* __restrict__ fc1b,
          const float* __restrict__ fc2w, const float* __restrict__ fc2b,
          float* __restrict__ out) {
    int g = threadIdx.x;
    if (g >= N_GRAPHS) return;
    float inv = 1.0f / fmaxf(cnt[g], 1.0f);
    float hg[20];
    for (int c = 0; c < 20; ++c) hg[c] = pool[g * 20 + c] * inv;
    float o = fc2b[0];
    for (int j = 0; j < 10; ++j) {
        float t = fc1b[j];
        for (int c = 0; c < 20; ++c) t = fmaf(hg[c], fc1w[c * 10 + j], t);
        o = fmaf(fmaxf(t, 0.f), fc2w[j], o);
    }
    out[g] = o;
}

// ---------------------------------------------------------------------------
extern "C" void kernel_launch(void* const* d_in, const int* in_sizes, int n_in,
                              void* d_out, int out_size, void* d_ws, size_t ws_size,
                              hipStream_t stream) {
    const float* feat   = (const float*)d_in[0];
    const float* Wself1 = (const float*)d_in[1];
    const float* Wneigh1= (const float*)d_in[2];
    const float* b1     = (const float*)d_in[3];
    const float* Wself2 = (const float*)d_in[4];
    const float* Wneigh2= (const float*)d_in[5];
    const float* b2     = (const float*)d_in[6];
    const float* fc1w   = (const float*)d_in[7];
    const float* fc1b   = (const float*)d_in[8];
    const float* fc2w   = (const float*)d_in[9];
    const float* fc2b   = (const float*)d_in[10];
    const int*   src    = (const int*)d_in[11];
    const int*   dst    = (const int*)d_in[12];
    const int*   gids   = (const int*)d_in[13];
    float* ws = (float*)d_ws;

    // workspace layout (floats); N1 region recycled for S2/N2, A1 region for A2
    float* S1 = ws;                        // 10,000,000
    float* N1 = ws + 10000000;             // 10,000,000
    float* A1 = ws + 20000000;             // 10,000,000
    float* S2 = N1;                        //  2,000,000 (N1 dead after aggregate1+gemm2 reads)
    float* N2 = N1 + 2000000;              //  2,000,000
    float* A2 = A1;                        //  2,000,000 (A1 dead after gemm2)
    int*   deg  = (int*)(ws + 30000000);   //    100,000
    float* pool = ws + 30100000;           //      1,280
    float* cnt  = ws + 30101280;           //         64
    int*   off  = (int*)(ws + 30101344);   //    100,000 (CSR end offsets after fill)
    int*   csr  = (int*)(ws + 30201344);   //    600,000 (CSR src indices)
    // total: 30,801,344 floats = ~117.5 MiB

    hipMemsetAsync(deg, 0, (100000 + 1280 + 64) * sizeof(float), stream);

    deg_count<<<(N_EDGES + 255) / 256, 256, 0, stream>>>(dst, deg);
    scan_off<<<1, 1024, 0, stream>>>(deg, off);
    csr_fill<<<(N_EDGES + 255) / 256, 256, 0, stream>>>(src, dst, off, csr);

    dim3 g1((N_NODES + 63) / 64, 4);
    gemm1<<<g1, 256, 0, stream>>>(feat, Wself1, Wneigh1, S1, N1);

    aggregate1<<<N_NODES / 2, 256, 0, stream>>>(N1, csr, off, A1);

    gemm2<<<(N_NODES + 63) / 64, 256, 0, stream>>>(S1, A1, deg, b1, Wself2, Wneigh2, S2, N2);

    aggregate2<<<(N_NODES + 7) / 8, 256, 0, stream>>>(N2, csr, off, A2);

    pool_kernel<<<(N_NODES + 255) / 256, 256, 0, stream>>>(S2, A2, deg, b2, gids, pool, cnt);

    head<<<1, 64, 0, stream>>>(pool, cnt, fc1w, fc1b, fc2w, fc2b, (float*)d_out);
}

// Round 2
// 398.110 us; speedup vs baseline: 1.4651x; 1.3783x over previous
//
#include <hip/hip_runtime.h>
#include <cstddef>

#define N_NODES  100000
#define N_EDGES  600000
#define N_GRAPHS 64

__device__ __forceinline__ void atomAddF(float* p, float v) {
    // gfx950 has HW global fp32 atomic add; unsafeAtomicAdd guarantees the HW path.
    unsafeAtomicAdd(p, v);
}

// ---------------------------------------------------------------------------
// deg[n] = in-degree (int)
__global__ __launch_bounds__(256) void deg_count(const int* __restrict__ dst,
                                                 int* __restrict__ deg) {
    int e = blockIdx.x * 256 + threadIdx.x;
    if (e < N_EDGES) atomicAdd(deg + dst[e], 1);
}

// ---------------------------------------------------------------------------
// alloc_ranges: parallel CSR range allocation. Order of node ranges is
// arbitrary (non-deterministic) -- only contiguity per node matters, since the
// aggregation is an unordered sum over each node's range. Each block scans its
// 256 degs (wave shfl scan + LDS combine) and grabs a base with ONE atomicAdd.
// Writes beg[n] (range start) and cur[n] (fill cursor, == beg initially).
__global__ __launch_bounds__(256)
void alloc_ranges(const int* __restrict__ deg, int* __restrict__ beg,
                  int* __restrict__ cur, int* __restrict__ counter) {
    int n = blockIdx.x * 256 + threadIdx.x;
    int d = (n < N_NODES) ? deg[n] : 0;
    int lane = threadIdx.x & 63, wid = threadIdx.x >> 6;
    // wave inclusive scan
    int incl = d;
#pragma unroll
    for (int o = 1; o < 64; o <<= 1) {
        int v = __shfl_up(incl, o);
        if (lane >= o) incl += v;
    }
    __shared__ int wsum[4];
    __shared__ int blockBase;
    if (lane == 63) wsum[wid] = incl;
    __syncthreads();
    if (threadIdx.x == 0) {
        int tot = wsum[0] + wsum[1] + wsum[2] + wsum[3];
        blockBase = atomicAdd(counter, tot);
    }
    __syncthreads();
    int base = blockBase;
    for (int w = 0; w < wid; ++w) base += wsum[w];
    int start = base + incl - d;
    if (n < N_NODES) { beg[n] = start; cur[n] = start; }
}

// ---------------------------------------------------------------------------
// CSR fill: csr_src[cur[d]++] = src[e].  Afterwards cur[n] = END offset.
__global__ __launch_bounds__(256)
void csr_fill(const int* __restrict__ src, const int* __restrict__ dst,
              int* __restrict__ cur, int* __restrict__ csr_src) {
    int e = blockIdx.x * 256 + threadIdx.x;
    if (e >= N_EDGES) return;
    int p = atomicAdd(cur + dst[e], 1);
    csr_src[p] = src[e];
}

// ---------------------------------------------------------------------------
// GEMM1: C[100000 x 200] = feat[100000 x 128] @ [Wself1 | Wneigh1]
// cols 0..99 -> S1, 100..199 -> N1.  BM=64, BN=64, 256 thr (16x16), TM=TN=4.
__global__ __launch_bounds__(256)
void gemm1(const float* __restrict__ feat, const float* __restrict__ Wself,
           const float* __restrict__ Wneigh,
           float* __restrict__ S1, float* __restrict__ N1) {
    __shared__ float As[64][132];   // [m][k], pad 132: A-col reads 2-way (free), rows 16B aligned
    __shared__ float Bs[128][64];   // [k][n]
    const int tid = threadIdx.x;
    const int m0  = blockIdx.x * 64;
    const int n0  = blockIdx.y * 64;   // 0,64,128,192

    // A tile: 64 rows x 32 float4 (k), coalesced
#pragma unroll
    for (int i = 0; i < 8; ++i) {
        int idx = tid + 256 * i;
        int r = idx >> 5, k4 = idx & 31;
        int gr = m0 + r;
        float4 v = make_float4(0.f, 0.f, 0.f, 0.f);
        if (gr < N_NODES)
            v = reinterpret_cast<const float4*>(feat)[(size_t)gr * 32 + k4];
        *reinterpret_cast<float4*>(&As[r][k4 * 4]) = v;
    }
    // B tile: 128 k x 16 float4 (n); cols >=200 zero-padded
#pragma unroll
    for (int i = 0; i < 8; ++i) {
        int idx = tid + 256 * i;
        int k = idx >> 4, n4 = idx & 15;
        int n = n0 + n4 * 4;
        float4 v = make_float4(0.f, 0.f, 0.f, 0.f);
        if (n < 100)       v = *reinterpret_cast<const float4*>(Wself + k * 100 + n);
        else if (n < 200)  v = *reinterpret_cast<const float4*>(Wneigh + k * 100 + (n - 100));
        *reinterpret_cast<float4*>(&Bs[k][n4 * 4]) = v;
    }
    __syncthreads();

    const int tr = tid >> 4, tc = tid & 15;
    float acc[4][4] = {};
#pragma unroll 4
    for (int k = 0; k < 128; ++k) {
        float a0 = As[tr * 4 + 0][k];
        float a1 = As[tr * 4 + 1][k];
        float a2 = As[tr * 4 + 2][k];
        float a3 = As[tr * 4 + 3][k];
        float4 b = *reinterpret_cast<const float4*>(&Bs[k][tc * 4]);
        acc[0][0] += a0 * b.x; acc[0][1] += a0 * b.y; acc[0][2] += a0 * b.z; acc[0][3] += a0 * b.w;
        acc[1][0] += a1 * b.x; acc[1][1] += a1 * b.y; acc[1][2] += a1 * b.z; acc[1][3] += a1 * b.w;
        acc[2][0] += a2 * b.x; acc[2][1] += a2 * b.y; acc[2][2] += a2 * b.z; acc[2][3] += a2 * b.w;
        acc[3][0] += a3 * b.x; acc[3][1] += a3 * b.y; acc[3][2] += a3 * b.z; acc[3][3] += a3 * b.w;
    }

#pragma unroll
    for (int i = 0; i < 4; ++i) {
        int gr = m0 + tr * 4 + i;
        if (gr >= N_NODES) continue;
        int n = n0 + tc * 4;
        float4 v = make_float4(acc[i][0], acc[i][1], acc[i][2], acc[i][3]);
        if (n < 100)       *reinterpret_cast<float4*>(S1 + (size_t)gr * 100 + n) = v;
        else if (n < 200)  *reinterpret_cast<float4*>(N1 + (size_t)gr * 100 + (n - 100)) = v;
    }
}

// ---------------------------------------------------------------------------
// aggregate1: A1[n][c] = sum over in-edges of N1[src][c].  Gather via CSR,
// zero float atomics, writes every row (zero-degree rows -> 0, replaces memset).
// 128 threads per node (100 live cols), 2 nodes per 256-block.
__global__ __launch_bounds__(256)
void aggregate1(const float* __restrict__ N1, const int* __restrict__ csr_src,
                const int* __restrict__ beg, const int* __restrict__ cur,
                float* __restrict__ A1) {
    int n = blockIdx.x * 2 + (threadIdx.x >> 7);
    int c = threadIdx.x & 127;
    if (n >= N_NODES || c >= 100) return;
    int b = beg[n];
    int end = cur[n];
    float acc = 0.f;
    int j = b;
    for (; j + 1 < end; j += 2) {           // unroll x2 for load pipelining
        int s0 = csr_src[j], s1 = csr_src[j + 1];
        acc += N1[(size_t)s0 * 100 + c] + N1[(size_t)s1 * 100 + c];
    }
    if (j < end) acc += N1[(size_t)csr_src[j] * 100 + c];
    A1[(size_t)n * 100 + c] = acc;
}

// ---------------------------------------------------------------------------
// GEMM2: h1 = relu(S1 + A1*inv_deg + b1) fused into A-tile load;
// C[100000 x 40] = h1 @ [Wself2 | Wneigh2].  BM=64, BN=64(40 live), K=100.
__global__ __launch_bounds__(256)
void gemm2(const float* __restrict__ S1, const float* __restrict__ A1,
           const int* __restrict__ deg, const float* __restrict__ b1,
           const float* __restrict__ Ws2, const float* __restrict__ Wn2,
           float* __restrict__ S2, float* __restrict__ N2) {
    __shared__ float As[64][108];   // [m][k], K=100 padded to 108 (aligned, 2-way reads)
    __shared__ float Bs[100][64];
    const int tid = threadIdx.x;
    const int m0  = blockIdx.x * 64;

    for (int idx = tid; idx < 100 * 16; idx += 256) {   // B tile
        int k = idx >> 4, n4 = idx & 15;
        int n = n4 * 4;
        float4 v = make_float4(0.f, 0.f, 0.f, 0.f);
        if (n < 20)       v = *reinterpret_cast<const float4*>(Ws2 + k * 20 + n);
        else if (n < 40)  v = *reinterpret_cast<const float4*>(Wn2 + k * 20 + (n - 20));
        *reinterpret_cast<float4*>(&Bs[k][n]) = v;
    }
    for (int idx = tid; idx < 64 * 25; idx += 256) {    // A tile (fused h1)
        int r = idx / 25, k4 = idx % 25;
        int gr = m0 + r;
        float4 h = make_float4(0.f, 0.f, 0.f, 0.f);
        if (gr < N_NODES) {
            float4 s  = *reinterpret_cast<const float4*>(S1 + (size_t)gr * 100 + k4 * 4);
            float4 a  = *reinterpret_cast<const float4*>(A1 + (size_t)gr * 100 + k4 * 4);
            float4 bb = *reinterpret_cast<const float4*>(b1 + k4 * 4);
            float inv = 1.0f / (float)max(deg[gr], 1);
            h.x = fmaxf(fmaf(a.x, inv, s.x) + bb.x, 0.f);
            h.y = fmaxf(fmaf(a.y, inv, s.y) + bb.y, 0.f);
            h.z = fmaxf(fmaf(a.z, inv, s.z) + bb.z, 0.f);
            h.w = fmaxf(fmaf(a.w, inv, s.w) + bb.w, 0.f);
        }
        *reinterpret_cast<float4*>(&As[r][k4 * 4]) = h;
    }
    __syncthreads();

    const int tr = tid >> 4, tc = tid & 15;
    float acc[4][4] = {};
#pragma unroll 4
    for (int k = 0; k < 100; ++k) {
        float a0 = As[tr * 4 + 0][k];
        float a1 = As[tr * 4 + 1][k];
        float a2 = As[tr * 4 + 2][k];
        float a3 = As[tr * 4 + 3][k];
        float4 b = *reinterpret_cast<const float4*>(&Bs[k][tc * 4]);
        acc[0][0] += a0 * b.x; acc[0][1] += a0 * b.y; acc[0][2] += a0 * b.z; acc[0][3] += a0 * b.w;
        acc[1][0] += a1 * b.x; acc[1][1] += a1 * b.y; acc[1][2] += a1 * b.z; acc[1][3] += a1 * b.w;
        acc[2][0] += a2 * b.x; acc[2][1] += a2 * b.y; acc[2][2] += a2 * b.z; acc[2][3] += a2 * b.w;
        acc[3][0] += a3 * b.x; acc[3][1] += a3 * b.y; acc[3][2] += a3 * b.z; acc[3][3] += a3 * b.w;
    }

#pragma unroll
    for (int i = 0; i < 4; ++i) {
        int gr = m0 + tr * 4 + i;
        if (gr >= N_NODES) continue;
        int n = tc * 4;
        float4 v = make_float4(acc[i][0], acc[i][1], acc[i][2], acc[i][3]);
        if (n < 20)       *reinterpret_cast<float4*>(S2 + (size_t)gr * 20 + n) = v;
        else if (n < 40)  *reinterpret_cast<float4*>(N2 + (size_t)gr * 20 + (n - 20)) = v;
    }
}

// ---------------------------------------------------------------------------
// aggregate2: A2[n][c] = sum over in-edges of N2[src][c].  32 thr/node (20 live),
// 8 nodes per 256-block.  Zero atomics, replaces scatter2 + A2 memset.
__global__ __launch_bounds__(256)
void aggregate2(const float* __restrict__ N2, const int* __restrict__ csr_src,
                const int* __restrict__ beg, const int* __restrict__ cur,
                float* __restrict__ A2) {
    int n = blockIdx.x * 8 + (threadIdx.x >> 5);
    int c = threadIdx.x & 31;
    if (n >= N_NODES || c >= 20) return;
    int b = beg[n];
    int end = cur[n];
    float acc = 0.f;
    int j = b;
    for (; j + 1 < end; j += 2) {
        int s0 = csr_src[j], s1 = csr_src[j + 1];
        acc += N2[(size_t)s0 * 20 + c] + N2[(size_t)s1 * 20 + c];
    }
    if (j < end) acc += N2[(size_t)csr_src[j] * 20 + c];
    A2[(size_t)n * 20 + c] = acc;
}

// ---------------------------------------------------------------------------
// pool: h2 = relu(S2 + A2*inv + b2); per-graph sums + counts.
// graph_ids sorted -> most waves uniform -> wave shfl-reduce, 20 atomics/wave.
__global__ __launch_bounds__(256)
void pool_kernel(const float* __restrict__ S2, const float* __restrict__ A2,
                 const int* __restrict__ deg, const float* __restrict__ b2,
                 const int* __restrict__ gids,
                 float* __restrict__ pool, float* __restrict__ cnt) {
    int n = blockIdx.x * 256 + threadIdx.x;
    float h[20];
    int g = -1;
    if (n < N_NODES) {
        g = gids[n];
        float inv = 1.0f / (float)max(deg[n], 1);
#pragma unroll
        for (int q = 0; q < 5; ++q) {
            float4 s = *reinterpret_cast<const float4*>(S2 + (size_t)n * 20 + q * 4);
            float4 a = *reinterpret_cast<const float4*>(A2 + (size_t)n * 20 + q * 4);
            float4 bb = *reinterpret_cast<const float4*>(b2 + q * 4);
            h[q * 4 + 0] = fmaxf(fmaf(a.x, inv, s.x) + bb.x, 0.f);
            h[q * 4 + 1] = fmaxf(fmaf(a.y, inv, s.y) + bb.y, 0.f);
            h[q * 4 + 2] = fmaxf(fmaf(a.z, inv, s.z) + bb.z, 0.f);
            h[q * 4 + 3] = fmaxf(fmaf(a.w, inv, s.w) + bb.w, 0.f);
        }
    } else {
#pragma unroll
        for (int c = 0; c < 20; ++c) h[c] = 0.f;
    }
    unsigned long long act = __ballot(n < N_NODES);
    int gfirst = __shfl(g, 0);
    bool uniform = __all(g == gfirst);
    if (uniform) {
        if (gfirst >= 0) {
#pragma unroll
            for (int c = 0; c < 20; ++c)
                for (int off2 = 32; off2 > 0; off2 >>= 1)
                    h[c] += __shfl_down(h[c], off2);
            if ((threadIdx.x & 63) == 0) {
                for (int c = 0; c < 20; ++c) atomAddF(&pool[gfirst * 20 + c], h[c]);
                atomAddF(&cnt[gfirst], (float)__popcll(act));
            }
        }
    } else if (n < N_NODES) {
        for (int c = 0; c < 20; ++c) atomAddF(&pool[g * 20 + c], h[c]);
        atomAddF(&cnt[g], 1.0f);
    }
}

// ---------------------------------------------------------------------------
// head: hg = pool/cnt; out = relu(hg@fc1+b1)@fc2+b2.  One block, thread per graph.
__global__ __launch_bounds__(64)
void head(const float* __restrict__ pool, const float* __restrict__ cnt,
          const float* __restrict__ fc1w, const float* __restrict__ fc1b,
          const float* __restrict__ fc2w, const float* __restrict__ fc2b,
          float* __restrict__ out) {
    int g = threadIdx.x;
    if (g >= N_GRAPHS) return;
    float inv = 1.0f / fmaxf(cnt[g], 1.0f);
    float hg[20];
    for (int c = 0; c < 20; ++c) hg[c] = pool[g * 20 + c] * inv;
    float o = fc2b[0];
    for (int j = 0; j < 10; ++j) {
        float t = fc1b[j];
        for (int c = 0; c < 20; ++c) t = fmaf(hg[c], fc1w[c * 10 + j], t);
        o = fmaf(fmaxf(t, 0.f), fc2w[j], o);
    }
    out[g] = o;
}

// ---------------------------------------------------------------------------
extern "C" void kernel_launch(void* const* d_in, const int* in_sizes, int n_in,
                              void* d_out, int out_size, void* d_ws, size_t ws_size,
                              hipStream_t stream) {
    const float* feat   = (const float*)d_in[0];
    const float* Wself1 = (const float*)d_in[1];
    const float* Wneigh1= (const float*)d_in[2];
    const float* b1     = (const float*)d_in[3];
    const float* Wself2 = (const float*)d_in[4];
    const float* Wneigh2= (const float*)d_in[5];
    const float* b2     = (const float*)d_in[6];
    const float* fc1w   = (const float*)d_in[7];
    const float* fc1b   = (const float*)d_in[8];
    const float* fc2w   = (const float*)d_in[9];
    const float* fc2b   = (const float*)d_in[10];
    const int*   src    = (const int*)d_in[11];
    const int*   dst    = (const int*)d_in[12];
    const int*   gids   = (const int*)d_in[13];
    float* ws = (float*)d_ws;

    // workspace layout (floats); N1 region recycled for S2/N2, A1 region for A2
    float* S1 = ws;                        // 10,000,000
    float* N1 = ws + 10000000;             // 10,000,000
    float* A1 = ws + 20000000;             // 10,000,000
    float* S2 = N1;                        //  2,000,000 (N1 dead after aggregate1+gemm2 reads)
    float* N2 = N1 + 2000000;              //  2,000,000
    float* A2 = A1;                        //  2,000,000 (A1 dead after gemm2)
    int*   deg  = (int*)(ws + 30000000);   //    100,000
    float* pool = ws + 30100000;           //      1,280
    float* cnt  = ws + 30101280;           //         64
    int*   ctr  = (int*)(ws + 30101344);   //          1 (range-alloc counter)
    int*   beg  = (int*)(ws + 30101360);   //    100,000 (CSR range starts)
    int*   cur  = (int*)(ws + 30201360);   //    100,000 (fill cursors -> range ends)
    int*   csr  = (int*)(ws + 30301360);   //    600,000 (CSR src indices)
    // total: 30,901,360 floats = ~117.9 MiB

    // zero deg + pool + cnt + ctr in one shot (contiguous region)
    hipMemsetAsync(deg, 0, (100000 + 1280 + 64 + 16) * sizeof(float), stream);

    deg_count<<<(N_EDGES + 255) / 256, 256, 0, stream>>>(dst, deg);
    alloc_ranges<<<(N_NODES + 255) / 256, 256, 0, stream>>>(deg, beg, cur, ctr);
    csr_fill<<<(N_EDGES + 255) / 256, 256, 0, stream>>>(src, dst, cur, csr);

    dim3 g1((N_NODES + 63) / 64, 4);
    gemm1<<<g1, 256, 0, stream>>>(feat, Wself1, Wneigh1, S1, N1);

    aggregate1<<<N_NODES / 2, 256, 0, stream>>>(N1, csr, beg, cur, A1);

    gemm2<<<(N_NODES + 63) / 64, 256, 0, stream>>>(S1, A1, deg, b1, Wself2, Wneigh2, S2, N2);

    aggregate2<<<(N_NODES + 7) / 8, 256, 0, stream>>>(N2, csr, beg, cur, A2);

    pool_kernel<<<(N_NODES + 255) / 256, 256, 0, stream>>>(S2, A2, deg, b2, gids, pool, cnt);

    head<<<1, 64, 0, stream>>>(pool, cnt, fc1w, fc1b, fc2w, fc2b, (float*)d_out);
}

// Round 3
// 390.764 us; speedup vs baseline: 1.4926x; 1.0188x over previous
//
#include <hip/hip_runtime.h>
#include <cstddef>

#define N_NODES  100000
#define N_EDGES  600000
#define N_GRAPHS 64

__device__ __forceinline__ void atomAddF(float* p, float v) {
    // gfx950 has HW global fp32 atomic add; unsafeAtomicAdd guarantees the HW path.
    unsafeAtomicAdd(p, v);
}

// ---------------------------------------------------------------------------
// deg[n] = in-degree (int)
__global__ __launch_bounds__(256) void deg_count(const int* __restrict__ dst,
                                                 int* __restrict__ deg) {
    int e = blockIdx.x * 256 + threadIdx.x;
    if (e < N_EDGES) atomicAdd(deg + dst[e], 1);
}

// ---------------------------------------------------------------------------
// alloc_ranges: parallel CSR range allocation. Order of node ranges is
// arbitrary (non-deterministic) -- only contiguity per node matters, since the
// aggregation is an unordered sum over each node's range. Each block scans its
// 256 degs (wave shfl scan + LDS combine) and grabs a base with ONE atomicAdd.
__global__ __launch_bounds__(256)
void alloc_ranges(const int* __restrict__ deg, int* __restrict__ beg,
                  int* __restrict__ cur, int* __restrict__ counter) {
    int n = blockIdx.x * 256 + threadIdx.x;
    int d = (n < N_NODES) ? deg[n] : 0;
    int lane = threadIdx.x & 63, wid = threadIdx.x >> 6;
    int incl = d;
#pragma unroll
    for (int o = 1; o < 64; o <<= 1) {
        int v = __shfl_up(incl, o);
        if (lane >= o) incl += v;
    }
    __shared__ int wsum[4];
    __shared__ int blockBase;
    if (lane == 63) wsum[wid] = incl;
    __syncthreads();
    if (threadIdx.x == 0) {
        int tot = wsum[0] + wsum[1] + wsum[2] + wsum[3];
        blockBase = atomicAdd(counter, tot);
    }
    __syncthreads();
    int base = blockBase;
    for (int w = 0; w < wid; ++w) base += wsum[w];
    int start = base + incl - d;
    if (n < N_NODES) { beg[n] = start; cur[n] = start; }
}

// ---------------------------------------------------------------------------
// CSR fill: csr_src[cur[d]++] = src[e].  Afterwards cur[n] = END offset.
__global__ __launch_bounds__(256)
void csr_fill(const int* __restrict__ src, const int* __restrict__ dst,
              int* __restrict__ cur, int* __restrict__ csr_src) {
    int e = blockIdx.x * 256 + threadIdx.x;
    if (e >= N_EDGES) return;
    int p = atomicAdd(cur + dst[e], 1);
    csr_src[p] = src[e];
}

// ---------------------------------------------------------------------------
// GEMM1: C[100000 x 200] = feat[100000 x 128] @ [Wself1 | Wneigh1]
// BM=256, BN=64, KB=32 (4 k-tiles), 256 thr (16x16), TM=16, TN=4.
// A tile stored TRANSPOSED in LDS ([k][m], stride 260) so the compute loop
// reads 4x ds_read_b128 for A + 1x for B per k-iter -> 5 LDS issues / 64 FMA.
// LDS = 33.3KB + 8KB -> 3 blocks/CU (12 waves). k ascending per output ->
// accumulation order identical to previous version (bitwise-same results).
__global__ __launch_bounds__(256, 3)
void gemm1(const float* __restrict__ feat, const float* __restrict__ Wself,
           const float* __restrict__ Wneigh,
           float* __restrict__ S1, float* __restrict__ N1) {
    __shared__ float Ast[32][260];  // [k][m] transposed; 260 = 256+4 (16B-aligned rows, spread banks)
    __shared__ float Bs[32][64];    // [k][n]
    const int tid = threadIdx.x;
    const int m0  = blockIdx.x * 256;
    const int n0  = blockIdx.y * 64;   // 0,64,128,192
    const int tr  = tid >> 4;          // 0..15
    const int tc  = tid & 15;          // 0..15

    float4 acc[16];
#pragma unroll
    for (int i = 0; i < 16; ++i) acc[i] = make_float4(0.f, 0.f, 0.f, 0.f);

    for (int kt = 0; kt < 4; ++kt) {
        const int k0 = kt * 32;
        if (kt) __syncthreads();        // protect previous tile's reads

        // A tile: 256 rows x 8 float4 of k, coalesced load, transposed store
#pragma unroll
        for (int i = 0; i < 8; ++i) {
            int idx = tid + 256 * i;            // 0..2047
            int r = idx >> 3, k4 = idx & 7;     // 8 float4 per row
            int gr = m0 + r;
            float4 v = make_float4(0.f, 0.f, 0.f, 0.f);
            if (gr < N_NODES)
                v = reinterpret_cast<const float4*>(feat)[(size_t)gr * 32 + (k0 >> 2) + k4];
            Ast[k4 * 4 + 0][r] = v.x;
            Ast[k4 * 4 + 1][r] = v.y;
            Ast[k4 * 4 + 2][r] = v.z;
            Ast[k4 * 4 + 3][r] = v.w;
        }
        // B tile: 32 k x 16 float4 (n); cols >=200 zero-padded
#pragma unroll
        for (int i = 0; i < 2; ++i) {
            int idx = tid + 256 * i;            // 0..511
            int k = idx >> 4, n4 = idx & 15;
            int n = n0 + n4 * 4;
            int gk = k0 + k;
            float4 v = make_float4(0.f, 0.f, 0.f, 0.f);
            if (n < 100)       v = *reinterpret_cast<const float4*>(Wself + gk * 100 + n);
            else if (n < 200)  v = *reinterpret_cast<const float4*>(Wneigh + gk * 100 + (n - 100));
            *reinterpret_cast<float4*>(&Bs[k][n4 * 4]) = v;
        }
        __syncthreads();

#pragma unroll 4
        for (int k = 0; k < 32; ++k) {
            const float4 b = *reinterpret_cast<const float4*>(&Bs[k][tc * 4]);
#pragma unroll
            for (int q = 0; q < 4; ++q) {
                const float4 a = *reinterpret_cast<const float4*>(&Ast[k][tr * 16 + q * 4]);
                acc[q * 4 + 0].x = fmaf(a.x, b.x, acc[q * 4 + 0].x);
                acc[q * 4 + 0].y = fmaf(a.x, b.y, acc[q * 4 + 0].y);
                acc[q * 4 + 0].z = fmaf(a.x, b.z, acc[q * 4 + 0].z);
                acc[q * 4 + 0].w = fmaf(a.x, b.w, acc[q * 4 + 0].w);
                acc[q * 4 + 1].x = fmaf(a.y, b.x, acc[q * 4 + 1].x);
                acc[q * 4 + 1].y = fmaf(a.y, b.y, acc[q * 4 + 1].y);
                acc[q * 4 + 1].z = fmaf(a.y, b.z, acc[q * 4 + 1].z);
                acc[q * 4 + 1].w = fmaf(a.y, b.w, acc[q * 4 + 1].w);
                acc[q * 4 + 2].x = fmaf(a.z, b.x, acc[q * 4 + 2].x);
                acc[q * 4 + 2].y = fmaf(a.z, b.y, acc[q * 4 + 2].y);
                acc[q * 4 + 2].z = fmaf(a.z, b.z, acc[q * 4 + 2].z);
                acc[q * 4 + 2].w = fmaf(a.z, b.w, acc[q * 4 + 2].w);
                acc[q * 4 + 3].x = fmaf(a.w, b.x, acc[q * 4 + 3].x);
                acc[q * 4 + 3].y = fmaf(a.w, b.y, acc[q * 4 + 3].y);
                acc[q * 4 + 3].z = fmaf(a.w, b.z, acc[q * 4 + 3].z);
                acc[q * 4 + 3].w = fmaf(a.w, b.w, acc[q * 4 + 3].w);
            }
        }
    }

#pragma unroll
    for (int i = 0; i < 16; ++i) {
        int gr = m0 + tr * 16 + i;
        if (gr >= N_NODES) continue;
        int n = n0 + tc * 4;
        if (n < 100)       *reinterpret_cast<float4*>(S1 + (size_t)gr * 100 + n) = acc[i];
        else if (n < 200)  *reinterpret_cast<float4*>(N1 + (size_t)gr * 100 + (n - 100)) = acc[i];
    }
}

// ---------------------------------------------------------------------------
// aggregate1: A1[n][c] = sum over in-edges of N1[src][c].  Gather via CSR,
// zero float atomics, writes every row (zero-degree rows -> 0).
__global__ __launch_bounds__(256)
void aggregate1(const float* __restrict__ N1, const int* __restrict__ csr_src,
                const int* __restrict__ beg, const int* __restrict__ cur,
                float* __restrict__ A1) {
    int n = blockIdx.x * 2 + (threadIdx.x >> 7);
    int c = threadIdx.x & 127;
    if (n >= N_NODES || c >= 100) return;
    int b = beg[n];
    int end = cur[n];
    float acc = 0.f;
    int j = b;
    for (; j + 1 < end; j += 2) {
        int s0 = csr_src[j], s1 = csr_src[j + 1];
        acc += N1[(size_t)s0 * 100 + c] + N1[(size_t)s1 * 100 + c];
    }
    if (j < end) acc += N1[(size_t)csr_src[j] * 100 + c];
    A1[(size_t)n * 100 + c] = acc;
}

// ---------------------------------------------------------------------------
// GEMM2: h1 = relu(S1 + A1*inv_deg + b1) fused into A-tile load;
// C[100000 x 40] = h1 @ [Wself2 | Wneigh2].  BM=64, BN=64(40 live), K=100.
__global__ __launch_bounds__(256)
void gemm2(const float* __restrict__ S1, const float* __restrict__ A1,
           const int* __restrict__ deg, const float* __restrict__ b1,
           const float* __restrict__ Ws2, const float* __restrict__ Wn2,
           float* __restrict__ S2, float* __restrict__ N2) {
    __shared__ float As[64][108];   // [m][k], K=100 padded to 108 (aligned, 2-way reads)
    __shared__ float Bs[100][64];
    const int tid = threadIdx.x;
    const int m0  = blockIdx.x * 64;

    for (int idx = tid; idx < 100 * 16; idx += 256) {   // B tile
        int k = idx >> 4, n4 = idx & 15;
        int n = n4 * 4;
        float4 v = make_float4(0.f, 0.f, 0.f, 0.f);
        if (n < 20)       v = *reinterpret_cast<const float4*>(Ws2 + k * 20 + n);
        else if (n < 40)  v = *reinterpret_cast<const float4*>(Wn2 + k * 20 + (n - 20));
        *reinterpret_cast<float4*>(&Bs[k][n]) = v;
    }
    for (int idx = tid; idx < 64 * 25; idx += 256) {    // A tile (fused h1)
        int r = idx / 25, k4 = idx % 25;
        int gr = m0 + r;
        float4 h = make_float4(0.f, 0.f, 0.f, 0.f);
        if (gr < N_NODES) {
            float4 s  = *reinterpret_cast<const float4*>(S1 + (size_t)gr * 100 + k4 * 4);
            float4 a  = *reinterpret_cast<const float4*>(A1 + (size_t)gr * 100 + k4 * 4);
            float4 bb = *reinterpret_cast<const float4*>(b1 + k4 * 4);
            float inv = 1.0f / (float)max(deg[gr], 1);
            h.x = fmaxf(fmaf(a.x, inv, s.x) + bb.x, 0.f);
            h.y = fmaxf(fmaf(a.y, inv, s.y) + bb.y, 0.f);
            h.z = fmaxf(fmaf(a.z, inv, s.z) + bb.z, 0.f);
            h.w = fmaxf(fmaf(a.w, inv, s.w) + bb.w, 0.f);
        }
        *reinterpret_cast<float4*>(&As[r][k4 * 4]) = h;
    }
    __syncthreads();

    const int tr = tid >> 4, tc = tid & 15;
    float acc[4][4] = {};
#pragma unroll 4
    for (int k = 0; k < 100; ++k) {
        float a0 = As[tr * 4 + 0][k];
        float a1 = As[tr * 4 + 1][k];
        float a2 = As[tr * 4 + 2][k];
        float a3 = As[tr * 4 + 3][k];
        float4 b = *reinterpret_cast<const float4*>(&Bs[k][tc * 4]);
        acc[0][0] += a0 * b.x; acc[0][1] += a0 * b.y; acc[0][2] += a0 * b.z; acc[0][3] += a0 * b.w;
        acc[1][0] += a1 * b.x; acc[1][1] += a1 * b.y; acc[1][2] += a1 * b.z; acc[1][3] += a1 * b.w;
        acc[2][0] += a2 * b.x; acc[2][1] += a2 * b.y; acc[2][2] += a2 * b.z; acc[2][3] += a2 * b.w;
        acc[3][0] += a3 * b.x; acc[3][1] += a3 * b.y; acc[3][2] += a3 * b.z; acc[3][3] += a3 * b.w;
    }

#pragma unroll
    for (int i = 0; i < 4; ++i) {
        int gr = m0 + tr * 4 + i;
        if (gr >= N_NODES) continue;
        int n = tc * 4;
        float4 v = make_float4(acc[i][0], acc[i][1], acc[i][2], acc[i][3]);
        if (n < 20)       *reinterpret_cast<float4*>(S2 + (size_t)gr * 20 + n) = v;
        else if (n < 40)  *reinterpret_cast<float4*>(N2 + (size_t)gr * 20 + (n - 20)) = v;
    }
}

// ---------------------------------------------------------------------------
// aggregate2: A2[n][c] = sum over in-edges of N2[src][c].  32 thr/node (20 live),
// 8 nodes per 256-block.  Zero atomics.
__global__ __launch_bounds__(256)
void aggregate2(const float* __restrict__ N2, const int* __restrict__ csr_src,
                const int* __restrict__ beg, const int* __restrict__ cur,
                float* __restrict__ A2) {
    int n = blockIdx.x * 8 + (threadIdx.x >> 5);
    int c = threadIdx.x & 31;
    if (n >= N_NODES || c >= 20) return;
    int b = beg[n];
    int end = cur[n];
    float acc = 0.f;
    int j = b;
    for (; j + 1 < end; j += 2) {
        int s0 = csr_src[j], s1 = csr_src[j + 1];
        acc += N2[(size_t)s0 * 20 + c] + N2[(size_t)s1 * 20 + c];
    }
    if (j < end) acc += N2[(size_t)csr_src[j] * 20 + c];
    A2[(size_t)n * 20 + c] = acc;
}

// ---------------------------------------------------------------------------
// pool: h2 = relu(S2 + A2*inv + b2); per-graph sums + counts.
// graph_ids sorted -> most waves uniform -> wave shfl-reduce, 20 atomics/wave.
__global__ __launch_bounds__(256)
void pool_kernel(const float* __restrict__ S2, const float* __restrict__ A2,
                 const int* __restrict__ deg, const float* __restrict__ b2,
                 const int* __restrict__ gids,
                 float* __restrict__ pool, float* __restrict__ cnt) {
    int n = blockIdx.x * 256 + threadIdx.x;
    float h[20];
    int g = -1;
    if (n < N_NODES) {
        g = gids[n];
        float inv = 1.0f / (float)max(deg[n], 1);
#pragma unroll
        for (int q = 0; q < 5; ++q) {
            float4 s = *reinterpret_cast<const float4*>(S2 + (size_t)n * 20 + q * 4);
            float4 a = *reinterpret_cast<const float4*>(A2 + (size_t)n * 20 + q * 4);
            float4 bb = *reinterpret_cast<const float4*>(b2 + q * 4);
            h[q * 4 + 0] = fmaxf(fmaf(a.x, inv, s.x) + bb.x, 0.f);
            h[q * 4 + 1] = fmaxf(fmaf(a.y, inv, s.y) + bb.y, 0.f);
            h[q * 4 + 2] = fmaxf(fmaf(a.z, inv, s.z) + bb.z, 0.f);
            h[q * 4 + 3] = fmaxf(fmaf(a.w, inv, s.w) + bb.w, 0.f);
        }
    } else {
#pragma unroll
        for (int c = 0; c < 20; ++c) h[c] = 0.f;
    }
    unsigned long long act = __ballot(n < N_NODES);
    int gfirst = __shfl(g, 0);
    bool uniform = __all(g == gfirst);
    if (uniform) {
        if (gfirst >= 0) {
#pragma unroll
            for (int c = 0; c < 20; ++c)
                for (int off2 = 32; off2 > 0; off2 >>= 1)
                    h[c] += __shfl_down(h[c], off2);
            if ((threadIdx.x & 63) == 0) {
                for (int c = 0; c < 20; ++c) atomAddF(&pool[gfirst * 20 + c], h[c]);
                atomAddF(&cnt[gfirst], (float)__popcll(act));
            }
        }
    } else if (n < N_NODES) {
        for (int c = 0; c < 20; ++c) atomAddF(&pool[g * 20 + c], h[c]);
        atomAddF(&cnt[g], 1.0f);
    }
}

// ---------------------------------------------------------------------------
// head: hg = pool/cnt; out = relu(hg@fc1+b1)@fc2+b2.  One block, thread per graph.
__global__ __launch_bounds__(64)
void head(const float* __restrict__ pool, const float* __restrict__ cnt,
          const float* __restrict__ fc1w, const float* __restrict__ fc1b,
          const float* __restrict__ fc2w, const float* __restrict__ fc2b,
          float* __restrict__ out) {
    int g = threadIdx.x;
    if (g >= N_GRAPHS) return;
    float inv = 1.0f / fmaxf(cnt[g], 1.0f);
    float hg[20];
    for (int c = 0; c < 20; ++c) hg[c] = pool[g * 20 + c] * inv;
    float o = fc2b[0];
    for (int j = 0; j < 10; ++j) {
        float t = fc1b[j];
        for (int c = 0; c < 20; ++c) t = fmaf(hg[c], fc1w[c * 10 + j], t);
        o = fmaf(fmaxf(t, 0.f), fc2w[j], o);
    }
    out[g] = o;
}

// ---------------------------------------------------------------------------
extern "C" void kernel_launch(void* const* d_in, const int* in_sizes, int n_in,
                              void* d_out, int out_size, void* d_ws, size_t ws_size,
                              hipStream_t stream) {
    const float* feat   = (const float*)d_in[0];
    const float* Wself1 = (const float*)d_in[1];
    const float* Wneigh1= (const float*)d_in[2];
    const float* b1     = (const float*)d_in[3];
    const float* Wself2 = (const float*)d_in[4];
    const float* Wneigh2= (const float*)d_in[5];
    const float* b2     = (const float*)d_in[6];
    const float* fc1w   = (const float*)d_in[7];
    const float* fc1b   = (const float*)d_in[8];
    const float* fc2w   = (const float*)d_in[9];
    const float* fc2b   = (const float*)d_in[10];
    const int*   src    = (const int*)d_in[11];
    const int*   dst    = (const int*)d_in[12];
    const int*   gids   = (const int*)d_in[13];
    float* ws = (float*)d_ws;

    // workspace layout (floats); N1 region recycled for S2/N2, A1 region for A2
    float* S1 = ws;                        // 10,000,000
    float* N1 = ws + 10000000;             // 10,000,000
    float* A1 = ws + 20000000;             // 10,000,000
    float* S2 = N1;                        //  2,000,000 (N1 dead after aggregate1+gemm2 reads)
    float* N2 = N1 + 2000000;              //  2,000,000
    float* A2 = A1;                        //  2,000,000 (A1 dead after gemm2)
    int*   deg  = (int*)(ws + 30000000);   //    100,000
    float* pool = ws + 30100000;           //      1,280
    float* cnt  = ws + 30101280;           //         64
    int*   ctr  = (int*)(ws + 30101344);   //          1 (range-alloc counter)
    int*   beg  = (int*)(ws + 30101360);   //    100,000 (CSR range starts)
    int*   cur  = (int*)(ws + 30201360);   //    100,000 (fill cursors -> range ends)
    int*   csr  = (int*)(ws + 30301360);   //    600,000 (CSR src indices)
    // total: 30,901,360 floats = ~117.9 MiB

    // zero deg + pool + cnt + ctr in one shot (contiguous region)
    hipMemsetAsync(deg, 0, (100000 + 1280 + 64 + 16) * sizeof(float), stream);

    deg_count<<<(N_EDGES + 255) / 256, 256, 0, stream>>>(dst, deg);
    alloc_ranges<<<(N_NODES + 255) / 256, 256, 0, stream>>>(deg, beg, cur, ctr);
    csr_fill<<<(N_EDGES + 255) / 256, 256, 0, stream>>>(src, dst, cur, csr);

    dim3 g1((N_NODES + 255) / 256, 4);
    gemm1<<<g1, 256, 0, stream>>>(feat, Wself1, Wneigh1, S1, N1);

    aggregate1<<<N_NODES / 2, 256, 0, stream>>>(N1, csr, beg, cur, A1);

    gemm2<<<(N_NODES + 63) / 64, 256, 0, stream>>>(S1, A1, deg, b1, Wself2, Wneigh2, S2, N2);

    aggregate2<<<(N_NODES + 7) / 8, 256, 0, stream>>>(N2, csr, beg, cur, A2);

    pool_kernel<<<(N_NODES + 255) / 256, 256, 0, stream>>>(S2, A2, deg, b2, gids, pool, cnt);

    head<<<1, 64, 0, stream>>>(pool, cnt, fc1w, fc1b, fc2w, fc2b, (float*)d_out);
}

// Round 4
// 344.381 us; speedup vs baseline: 1.6936x; 1.1347x over previous
//
#include <hip/hip_runtime.h>
#include <cstddef>

#define N_NODES  100000
#define N_EDGES  600000
#define N_GRAPHS 64

__device__ __forceinline__ void atomAddF(float* p, float v) {
    // gfx950 has HW global fp32 atomic add; unsafeAtomicAdd guarantees the HW path.
    unsafeAtomicAdd(p, v);
}

// global -> LDS direct DMA, 16B per lane. Dest must be wave-uniform base;
// HW writes lane l at base + l*16. Global src address is per-lane.
typedef __attribute__((address_space(1))) void GV;
typedef __attribute__((address_space(3))) void LV;
__device__ __forceinline__ void gload16(const float* g, float* l) {
    __builtin_amdgcn_global_load_lds((GV*)g, (LV*)l, 16, 0, 0);
}

// ---------------------------------------------------------------------------
// deg[n] = in-degree (int)
__global__ __launch_bounds__(256) void deg_count(const int* __restrict__ dst,
                                                 int* __restrict__ deg) {
    int e = blockIdx.x * 256 + threadIdx.x;
    if (e < N_EDGES) atomicAdd(deg + dst[e], 1);
}

// ---------------------------------------------------------------------------
// alloc_ranges: parallel CSR range allocation (order of node ranges arbitrary;
// only per-node contiguity matters for an unordered sum).
__global__ __launch_bounds__(256)
void alloc_ranges(const int* __restrict__ deg, int* __restrict__ beg,
                  int* __restrict__ cur, int* __restrict__ counter) {
    int n = blockIdx.x * 256 + threadIdx.x;
    int d = (n < N_NODES) ? deg[n] : 0;
    int lane = threadIdx.x & 63, wid = threadIdx.x >> 6;
    int incl = d;
#pragma unroll
    for (int o = 1; o < 64; o <<= 1) {
        int v = __shfl_up(incl, o);
        if (lane >= o) incl += v;
    }
    __shared__ int wsum[4];
    __shared__ int blockBase;
    if (lane == 63) wsum[wid] = incl;
    __syncthreads();
    if (threadIdx.x == 0) {
        int tot = wsum[0] + wsum[1] + wsum[2] + wsum[3];
        blockBase = atomicAdd(counter, tot);
    }
    __syncthreads();
    int base = blockBase;
    for (int w = 0; w < wid; ++w) base += wsum[w];
    int start = base + incl - d;
    if (n < N_NODES) { beg[n] = start; cur[n] = start; }
}

// ---------------------------------------------------------------------------
// CSR fill: csr_src[cur[d]++] = src[e].  Afterwards cur[n] = END offset.
__global__ __launch_bounds__(256)
void csr_fill(const int* __restrict__ src, const int* __restrict__ dst,
              int* __restrict__ cur, int* __restrict__ csr_src) {
    int e = blockIdx.x * 256 + threadIdx.x;
    if (e >= N_EDGES) return;
    int p = atomicAdd(cur + dst[e], 1);
    csr_src[p] = src[e];
}

// ---------------------------------------------------------------------------
// GEMM1: C[100000 x 200] = feat[100000 x 128] @ [Wself1 | Wneigh1]
// BM=128, BN=64, KB=32 (4 k-tiles), 256 thr (16 tr x 16 tc), TM=8, TN=4.
// A staged by global_load_lds (16B/lane, zero staging VALU / zero ds_writes).
// LDS dest is linear (HW constraint); conflict-free scalar A-reads achieved by
// pre-swizzling the GLOBAL source: chunk k4c in LDS holds global chunk
// k4 = k4c ^ ((row>>3)&3).  A-read banks then differ across the wave's 4 tr
// groups (each address broadcast x16 lanes -> conflict-free); global loads stay
// within one cacheline per 8-lane row group (coalesced).
// LDS = 16KB (A) + 8KB (B) = 24KB -> 6 blocks/CU = 24 waves (75% occupancy).
__global__ __launch_bounds__(256, 6)
void gemm1(const float* __restrict__ feat, const float* __restrict__ Wself,
           const float* __restrict__ Wneigh,
           float* __restrict__ S1, float* __restrict__ N1) {
    __shared__ float As[128 * 32];  // linear; unit u (16B) = r*8 + k4c
    __shared__ float Bs[32][64];
    const int tid  = threadIdx.x;
    const int m0   = blockIdx.x * 128;
    const int n0   = blockIdx.y * 64;   // 0,64,128,192
    const int wave = tid >> 6;
    const int lane = tid & 63;
    const int tr   = tid >> 4;          // 0..15 (rows tr*8 .. tr*8+7)
    const int tc   = tid & 15;          // cols n0 + tc*4 .. +3

    // per-lane A source indices (constant across k-tiles except k0)
    const int u   = (wave * 4) * 64 + lane;          // first of 4 chunks, stride 256 units
    float4 acc[8];
#pragma unroll
    for (int i = 0; i < 8; ++i) acc[i] = make_float4(0.f, 0.f, 0.f, 0.f);

    for (int kt = 0; kt < 4; ++kt) {
        const int k0 = kt * 32;
        if (kt) __syncthreads();        // previous tile's reads done before overwrite

        // A tile: 1024 16B-chunks, 4 global_load_lds per wave
#pragma unroll
        for (int t = 0; t < 4; ++t) {
            int uu  = u + t * 64;                    // 0..1023
            int r   = uu >> 3;
            int k4c = uu & 7;
            int k4  = k4c ^ ((r >> 3) & 3);          // source pre-swizzle
            int gr  = m0 + r; if (gr >= N_NODES) gr = N_NODES - 1;  // clamp: rows >=N discarded at C-write
            gload16(feat + (size_t)gr * 128 + k0 + k4 * 4, &As[(wave * 4 + t) * 256]);
        }
        // B tile: 32 k x 16 float4 (n); cols >=200 zero-padded
#pragma unroll
        for (int i = 0; i < 2; ++i) {
            int idx = tid + 256 * i;                 // 0..511
            int k = idx >> 4, n4 = idx & 15;
            int n = n0 + n4 * 4;
            int gk = k0 + k;
            float4 v = make_float4(0.f, 0.f, 0.f, 0.f);
            if (n < 100)       v = *reinterpret_cast<const float4*>(Wself + gk * 100 + n);
            else if (n < 200)  v = *reinterpret_cast<const float4*>(Wneigh + gk * 100 + (n - 100));
            *reinterpret_cast<float4*>(&Bs[k][n4 * 4]) = v;
        }
        __syncthreads();    // drains vmcnt (gload_lds) + lgkm, then barrier

        const int abase = tr * 256;                  // (tr*8)*32
        const int sw    = tr & 3;
#pragma unroll 8
        for (int k = 0; k < 32; ++k) {
            const float4 b = *reinterpret_cast<const float4*>(&Bs[k][tc * 4]);
            const int kc = ((k >> 2) ^ sw) * 4 + (k & 3);
#pragma unroll
            for (int i = 0; i < 8; ++i) {
                const float a = As[abase + i * 32 + kc];
                acc[i].x = fmaf(a, b.x, acc[i].x);
                acc[i].y = fmaf(a, b.y, acc[i].y);
                acc[i].z = fmaf(a, b.z, acc[i].z);
                acc[i].w = fmaf(a, b.w, acc[i].w);
            }
        }
    }

#pragma unroll
    for (int i = 0; i < 8; ++i) {
        int gr = m0 + tr * 8 + i;
        if (gr >= N_NODES) continue;
        int n = n0 + tc * 4;
        if (n < 100)       *reinterpret_cast<float4*>(S1 + (size_t)gr * 100 + n) = acc[i];
        else if (n < 200)  *reinterpret_cast<float4*>(N1 + (size_t)gr * 100 + (n - 100)) = acc[i];
    }
}

// ---------------------------------------------------------------------------
// aggregate1: A1[n][c] = sum over in-edges of N1[src][c].  float4 per lane:
// 8 nodes per 256-block, 32 lanes/node (25 live), 4x fewer load instructions
// than scalar on this latency-bound L2/L3 gather.  Pairwise accumulation
// order preserved.  Zero float atomics; writes every row.
__global__ __launch_bounds__(256)
void aggregate1(const float* __restrict__ N1, const int* __restrict__ csr_src,
                const int* __restrict__ beg, const int* __restrict__ cur,
                float* __restrict__ A1) {
    int n  = blockIdx.x * 8 + (threadIdx.x >> 5);
    int c4 = threadIdx.x & 31;
    if (n >= N_NODES || c4 >= 25) return;
    int b = beg[n], end = cur[n];
    float4 acc = make_float4(0.f, 0.f, 0.f, 0.f);
    int j = b;
    for (; j + 1 < end; j += 2) {
        int s0 = csr_src[j], s1 = csr_src[j + 1];
        float4 v0 = *reinterpret_cast<const float4*>(N1 + (size_t)s0 * 100 + c4 * 4);
        float4 v1 = *reinterpret_cast<const float4*>(N1 + (size_t)s1 * 100 + c4 * 4);
        acc.x += v0.x + v1.x; acc.y += v0.y + v1.y;
        acc.z += v0.z + v1.z; acc.w += v0.w + v1.w;
    }
    if (j < end) {
        int s = csr_src[j];
        float4 v = *reinterpret_cast<const float4*>(N1 + (size_t)s * 100 + c4 * 4);
        acc.x += v.x; acc.y += v.y; acc.z += v.z; acc.w += v.w;
    }
    *reinterpret_cast<float4*>(A1 + (size_t)n * 100 + c4 * 4) = acc;
}

// ---------------------------------------------------------------------------
// GEMM2: h1 = relu(S1 + A1*inv_deg + b1) fused into A-tile load;
// C[100000 x 40] = h1 @ [Wself2 | Wneigh2].  BM=64, BN=64(40 live), K=100.
__global__ __launch_bounds__(256)
void gemm2(const float* __restrict__ S1, const float* __restrict__ A1,
           const int* __restrict__ deg, const float* __restrict__ b1,
           const float* __restrict__ Ws2, const float* __restrict__ Wn2,
           float* __restrict__ S2, float* __restrict__ N2) {
    __shared__ float As[64][108];   // [m][k], K=100 padded to 108 (aligned, 2-way reads)
    __shared__ float Bs[100][64];
    const int tid = threadIdx.x;
    const int m0  = blockIdx.x * 64;

    for (int idx = tid; idx < 100 * 16; idx += 256) {   // B tile
        int k = idx >> 4, n4 = idx & 15;
        int n = n4 * 4;
        float4 v = make_float4(0.f, 0.f, 0.f, 0.f);
        if (n < 20)       v = *reinterpret_cast<const float4*>(Ws2 + k * 20 + n);
        else if (n < 40)  v = *reinterpret_cast<const float4*>(Wn2 + k * 20 + (n - 20));
        *reinterpret_cast<float4*>(&Bs[k][n]) = v;
    }
    for (int idx = tid; idx < 64 * 25; idx += 256) {    // A tile (fused h1)
        int r = idx / 25, k4 = idx % 25;
        int gr = m0 + r;
        float4 h = make_float4(0.f, 0.f, 0.f, 0.f);
        if (gr < N_NODES) {
            float4 s  = *reinterpret_cast<const float4*>(S1 + (size_t)gr * 100 + k4 * 4);
            float4 a  = *reinterpret_cast<const float4*>(A1 + (size_t)gr * 100 + k4 * 4);
            float4 bb = *reinterpret_cast<const float4*>(b1 + k4 * 4);
            float inv = 1.0f / (float)max(deg[gr], 1);
            h.x = fmaxf(fmaf(a.x, inv, s.x) + bb.x, 0.f);
            h.y = fmaxf(fmaf(a.y, inv, s.y) + bb.y, 0.f);
            h.z = fmaxf(fmaf(a.z, inv, s.z) + bb.z, 0.f);
            h.w = fmaxf(fmaf(a.w, inv, s.w) + bb.w, 0.f);
        }
        *reinterpret_cast<float4*>(&As[r][k4 * 4]) = h;
    }
    __syncthreads();

    const int tr = tid >> 4, tc = tid & 15;
    float acc[4][4] = {};
#pragma unroll 4
    for (int k = 0; k < 100; ++k) {
        float a0 = As[tr * 4 + 0][k];
        float a1 = As[tr * 4 + 1][k];
        float a2 = As[tr * 4 + 2][k];
        float a3 = As[tr * 4 + 3][k];
        float4 b = *reinterpret_cast<const float4*>(&Bs[k][tc * 4]);
        acc[0][0] += a0 * b.x; acc[0][1] += a0 * b.y; acc[0][2] += a0 * b.z; acc[0][3] += a0 * b.w;
        acc[1][0] += a1 * b.x; acc[1][1] += a1 * b.y; acc[1][2] += a1 * b.z; acc[1][3] += a1 * b.w;
        acc[2][0] += a2 * b.x; acc[2][1] += a2 * b.y; acc[2][2] += a2 * b.z; acc[2][3] += a2 * b.w;
        acc[3][0] += a3 * b.x; acc[3][1] += a3 * b.y; acc[3][2] += a3 * b.z; acc[3][3] += a3 * b.w;
    }

#pragma unroll
    for (int i = 0; i < 4; ++i) {
        int gr = m0 + tr * 4 + i;
        if (gr >= N_NODES) continue;
        int n = tc * 4;
        float4 v = make_float4(acc[i][0], acc[i][1], acc[i][2], acc[i][3]);
        if (n < 20)       *reinterpret_cast<float4*>(S2 + (size_t)gr * 20 + n) = v;
        else if (n < 40)  *reinterpret_cast<float4*>(N2 + (size_t)gr * 20 + (n - 20)) = v;
    }
}

// ---------------------------------------------------------------------------
// aggregate2: A2[n][c] = sum over in-edges of N2[src][c].  float4 per lane:
// 32 nodes per 256-block, 8 lanes/node (5 live).  Zero atomics.
__global__ __launch_bounds__(256)
void aggregate2(const float* __restrict__ N2, const int* __restrict__ csr_src,
                const int* __restrict__ beg, const int* __restrict__ cur,
                float* __restrict__ A2) {
    int n  = blockIdx.x * 32 + (threadIdx.x >> 3);
    int c4 = threadIdx.x & 7;
    if (n >= N_NODES || c4 >= 5) return;
    int b = beg[n], end = cur[n];
    float4 acc = make_float4(0.f, 0.f, 0.f, 0.f);
    int j = b;
    for (; j + 1 < end; j += 2) {
        int s0 = csr_src[j], s1 = csr_src[j + 1];
        float4 v0 = *reinterpret_cast<const float4*>(N2 + (size_t)s0 * 20 + c4 * 4);
        float4 v1 = *reinterpret_cast<const float4*>(N2 + (size_t)s1 * 20 + c4 * 4);
        acc.x += v0.x + v1.x; acc.y += v0.y + v1.y;
        acc.z += v0.z + v1.z; acc.w += v0.w + v1.w;
    }
    if (j < end) {
        int s = csr_src[j];
        float4 v = *reinterpret_cast<const float4*>(N2 + (size_t)s * 20 + c4 * 4);
        acc.x += v.x; acc.y += v.y; acc.z += v.z; acc.w += v.w;
    }
    *reinterpret_cast<float4*>(A2 + (size_t)n * 20 + c4 * 4) = acc;
}

// ---------------------------------------------------------------------------
// pool: h2 = relu(S2 + A2*inv + b2); per-graph sums + counts.
// graph_ids sorted -> most waves uniform -> wave shfl-reduce, 20 atomics/wave.
__global__ __launch_bounds__(256)
void pool_kernel(const float* __restrict__ S2, const float* __restrict__ A2,
                 const int* __restrict__ deg, const float* __restrict__ b2,
                 const int* __restrict__ gids,
                 float* __restrict__ pool, float* __restrict__ cnt) {
    int n = blockIdx.x * 256 + threadIdx.x;
    float h[20];
    int g = -1;
    if (n < N_NODES) {
        g = gids[n];
        float inv = 1.0f / (float)max(deg[n], 1);
#pragma unroll
        for (int q = 0; q < 5; ++q) {
            float4 s = *reinterpret_cast<const float4*>(S2 + (size_t)n * 20 + q * 4);
            float4 a = *reinterpret_cast<const float4*>(A2 + (size_t)n * 20 + q * 4);
            float4 bb = *reinterpret_cast<const float4*>(b2 + q * 4);
            h[q * 4 + 0] = fmaxf(fmaf(a.x, inv, s.x) + bb.x, 0.f);
            h[q * 4 + 1] = fmaxf(fmaf(a.y, inv, s.y) + bb.y, 0.f);
            h[q * 4 + 2] = fmaxf(fmaf(a.z, inv, s.z) + bb.z, 0.f);
            h[q * 4 + 3] = fmaxf(fmaf(a.w, inv, s.w) + bb.w, 0.f);
        }
    } else {
#pragma unroll
        for (int c = 0; c < 20; ++c) h[c] = 0.f;
    }
    unsigned long long act = __ballot(n < N_NODES);
    int gfirst = __shfl(g, 0);
    bool uniform = __all(g == gfirst);
    if (uniform) {
        if (gfirst >= 0) {
#pragma unroll
            for (int c = 0; c < 20; ++c)
                for (int off2 = 32; off2 > 0; off2 >>= 1)
                    h[c] += __shfl_down(h[c], off2);
            if ((threadIdx.x & 63) == 0) {
                for (int c = 0; c < 20; ++c) atomAddF(&pool[gfirst * 20 + c], h[c]);
                atomAddF(&cnt[gfirst], (float)__popcll(act));
            }
        }
    } else if (n < N_NODES) {
        for (int c = 0; c < 20; ++c) atomAddF(&pool[g * 20 + c], h[c]);
        atomAddF(&cnt[g], 1.0f);
    }
}

// ---------------------------------------------------------------------------
// head: hg = pool/cnt; out = relu(hg@fc1+b1)@fc2+b2.  One block, thread per graph.
__global__ __launch_bounds__(64)
void head(const float* __restrict__ pool, const float* __restrict__ cnt,
          const float* __restrict__ fc1w, const float* __restrict__ fc1b,
          const float* __restrict__ fc2w, const float* __restrict__ fc2b,
          float* __restrict__ out) {
    int g = threadIdx.x;
    if (g >= N_GRAPHS) return;
    float inv = 1.0f / fmaxf(cnt[g], 1.0f);
    float hg[20];
    for (int c = 0; c < 20; ++c) hg[c] = pool[g * 20 + c] * inv;
    float o = fc2b[0];
    for (int j = 0; j < 10; ++j) {
        float t = fc1b[j];
        for (int c = 0; c < 20; ++c) t = fmaf(hg[c], fc1w[c * 10 + j], t);
        o = fmaf(fmaxf(t, 0.f), fc2w[j], o);
    }
    out[g] = o;
}

// ---------------------------------------------------------------------------
extern "C" void kernel_launch(void* const* d_in, const int* in_sizes, int n_in,
                              void* d_out, int out_size, void* d_ws, size_t ws_size,
                              hipStream_t stream) {
    const float* feat   = (const float*)d_in[0];
    const float* Wself1 = (const float*)d_in[1];
    const float* Wneigh1= (const float*)d_in[2];
    const float* b1     = (const float*)d_in[3];
    const float* Wself2 = (const float*)d_in[4];
    const float* Wneigh2= (const float*)d_in[5];
    const float* b2     = (const float*)d_in[6];
    const float* fc1w   = (const float*)d_in[7];
    const float* fc1b   = (const float*)d_in[8];
    const float* fc2w   = (const float*)d_in[9];
    const float* fc2b   = (const float*)d_in[10];
    const int*   src    = (const int*)d_in[11];
    const int*   dst    = (const int*)d_in[12];
    const int*   gids   = (const int*)d_in[13];
    float* ws = (float*)d_ws;

    // workspace layout (floats); N1 region recycled for S2/N2, A1 region for A2
    float* S1 = ws;                        // 10,000,000
    float* N1 = ws + 10000000;             // 10,000,000
    float* A1 = ws + 20000000;             // 10,000,000
    float* S2 = N1;                        //  2,000,000 (N1 dead after aggregate1+gemm2 reads)
    float* N2 = N1 + 2000000;              //  2,000,000
    float* A2 = A1;                        //  2,000,000 (A1 dead after gemm2)
    int*   deg  = (int*)(ws + 30000000);   //    100,000
    float* pool = ws + 30100000;           //      1,280
    float* cnt  = ws + 30101280;           //         64
    int*   ctr  = (int*)(ws + 30101344);   //          1 (range-alloc counter)
    int*   beg  = (int*)(ws + 30101360);   //    100,000 (CSR range starts)
    int*   cur  = (int*)(ws + 30201360);   //    100,000 (fill cursors -> range ends)
    int*   csr  = (int*)(ws + 30301360);   //    600,000 (CSR src indices)
    // total: 30,901,360 floats = ~117.9 MiB

    // zero deg + pool + cnt + ctr in one shot (contiguous region)
    hipMemsetAsync(deg, 0, (100000 + 1280 + 64 + 16) * sizeof(float), stream);

    deg_count<<<(N_EDGES + 255) / 256, 256, 0, stream>>>(dst, deg);
    alloc_ranges<<<(N_NODES + 255) / 256, 256, 0, stream>>>(deg, beg, cur, ctr);
    csr_fill<<<(N_EDGES + 255) / 256, 256, 0, stream>>>(src, dst, cur, csr);

    dim3 g1((N_NODES + 127) / 128, 4);
    gemm1<<<g1, 256, 0, stream>>>(feat, Wself1, Wneigh1, S1, N1);

    aggregate1<<<(N_NODES + 7) / 8, 256, 0, stream>>>(N1, csr, beg, cur, A1);

    gemm2<<<(N_NODES + 63) / 64, 256, 0, stream>>>(S1, A1, deg, b1, Wself2, Wneigh2, S2, N2);

    aggregate2<<<(N_NODES + 31) / 32, 256, 0, stream>>>(N2, csr, beg, cur, A2);

    pool_kernel<<<(N_NODES + 255) / 256, 256, 0, stream>>>(S2, A2, deg, b2, gids, pool, cnt);

    head<<<1, 64, 0, stream>>>(pool, cnt, fc1w, fc1b, fc2w, fc2b, (float*)d_out);
}